// Round 4
// baseline (1144.869 us; speedup 1.0000x reference)
//
#include <hip/hip_runtime.h>
#include <hip/hip_bf16.h>
#include <math.h>

#define DEVINL __device__ __forceinline__

typedef __bf16 bf16x8 __attribute__((ext_vector_type(8)));
typedef float  f32x4  __attribute__((ext_vector_type(4)));
typedef unsigned int u32x4 __attribute__((ext_vector_type(4)));

DEVINL float bf2f(unsigned short h){ return __builtin_bit_cast(float, (unsigned)h << 16); }
DEVINL unsigned short f2bf(float f){
  unsigned u = __builtin_bit_cast(unsigned, f);
  u += 0x7fffu + ((u >> 16) & 1u);
  return (unsigned short)(u >> 16);
}

// direct global->LDS DMA, 16B per lane (lds dest must be wave-uniform base + lane*16)
DEVINL void gl16(const unsigned short* g, unsigned short* l){
  __builtin_amdgcn_global_load_lds((const __attribute__((address_space(1))) unsigned int*)g,
                                   (__attribute__((address_space(3))) unsigned int*)l,
                                   16, 0, 0);
}

// 32-bit LDS byte offset for inline-asm DS ops
DEVINL unsigned ldsoff(const void* p){
  return (unsigned)(unsigned long long)(const __attribute__((address_space(3))) char*)p;
}
// inline-asm ds_read_b128: invisible to the backend waitcnt/alias tracker.
// Caller must place s_waitcnt lgkmcnt + sched_barrier before consumers (rule #18).
DEVINL bf16x8 dsr16(const unsigned short* p){
  u32x4 r;
  asm volatile("ds_read_b128 %0, %1" : "=v"(r) : "v"(ldsoff(p)));
  return __builtin_bit_cast(bf16x8, r);
}

// ---- problem constants ----
#define Bn 32
#define Hn 56
#define Wn 56
#define Cn 192
#define WSz 7
#define SHIFTn 3
#define HEADSn 6
#define HDn 32
#define NWIN 49
#define NPIX (Bn*Hn*Wn)       /* 100352 == 2048*49 */
#define HIDDENn 768
#define KCONV (9*Cn)          /* 1728 */
#define PADH 58
#define QKSCALE 0.17677669529663687f

DEVINL float wave_sum(float v){
  #pragma unroll
  for (int off=32; off; off>>=1) v += __shfl_xor(v, off, 64);
  return v;
}

// ---------------- LN1 (fp32 in) + roll(-3,-3) + window partition -> h [100352][192] bf16 ----------------
__global__ __launch_bounds__(256) void k_ln1(const float* __restrict__ x,
                                             const float* __restrict__ g,
                                             const float* __restrict__ bb,
                                             unsigned short* __restrict__ h)
{
  int row  = blockIdx.x*4 + (threadIdx.x >> 6);
  int lane = threadIdx.x & 63;
  int win = row / NWIN, n = row % NWIN;
  int b = win >> 6, rem = win & 63, wh = rem >> 3, ww = rem & 7;
  int i = n / WSz, j = n % WSz;
  int rr = (wh*WSz + i + SHIFTn) % Hn;
  int cc = (ww*WSz + j + SHIFTn) % Wn;
  const float* xr = x + (size_t)((b*Hn + rr)*Wn + cc)*Cn;
  float v0 = xr[lane], v1 = xr[lane+64], v2 = xr[lane+128];
  float s  = wave_sum(v0+v1+v2);
  float sq = wave_sum(v0*v0+v1*v1+v2*v2);
  float mu = s * (1.0f/Cn);
  float var = sq * (1.0f/Cn) - mu*mu;
  float rs = rsqrtf(var + 1e-3f);
  unsigned short* hr = h + (size_t)row*Cn;
  hr[lane]     = f2bf((v0-mu)*rs*g[lane]     + bb[lane]);
  hr[lane+64]  = f2bf((v1-mu)*rs*g[lane+64]  + bb[lane+64]);
  hr[lane+128] = f2bf((v2-mu)*rs*g[lane+128] + bb[lane+128]);
}

// ---------------- LN2 on xmid(fp32) -> zero-padded bf16 buffer [32][58][58][192] ----------------
__global__ __launch_bounds__(256) void k_ln2(const float* __restrict__ xmid,
                                             const float* __restrict__ g,
                                             const float* __restrict__ bb,
                                             unsigned short* __restrict__ out)
{
  int p    = blockIdx.x*4 + (threadIdx.x >> 6);
  int lane = threadIdx.x & 63;
  int b = p / (Hn*Wn), rc = p % (Hn*Wn);
  int r = rc / Wn, c = rc % Wn;
  const float* xr = xmid + (size_t)p*Cn;
  float v0 = xr[lane], v1 = xr[lane+64], v2 = xr[lane+128];
  float s  = wave_sum(v0+v1+v2);
  float sq = wave_sum(v0*v0+v1*v1+v2*v2);
  float mu = s * (1.0f/Cn);
  float var = sq * (1.0f/Cn) - mu*mu;
  float rs = rsqrtf(var + 1e-3f);
  unsigned short* orow = out + (size_t)((b*PADH + r + 1)*PADH + (c + 1))*Cn;
  orow[lane]     = f2bf((v0-mu)*rs*g[lane]     + bb[lane]);
  orow[lane+64]  = f2bf((v1-mu)*rs*g[lane+64]  + bb[lane+64]);
  orow[lane+128] = f2bf((v2-mu)*rs*g[lane+128] + bb[lane+128]);
}

// ---------------- transpose + fp32->bf16: out[n*K+k] = bf16(in[k*N+n]) ----------------
__global__ __launch_bounds__(256) void k_transpose(const float* __restrict__ in,
                                                   unsigned short* __restrict__ out,
                                                   int K, int N)
{
  int idx = blockIdx.x*256 + threadIdx.x;
  if (idx < K*N){ int k = idx / N, n = idx - k*N; out[(size_t)n*K + k] = f2bf(in[idx]); }
}

// ---------------- fused windowed attention: one block per (head, chunk-local window) ----------------
__global__ __launch_bounds__(256) void k_attn(const unsigned short* __restrict__ qkv, // chunk-local bf16
                                              const float* __restrict__ bias_table,   // fp32
                                              unsigned short* __restrict__ o,          // global rows bf16
                                              int win_base)
{
  __shared__ float qs[NWIN][HDn], ks[NWIN][HDn], vs[NWIN][HDn], S[NWIN][NWIN+1];
  int head = blockIdx.x, lwin = blockIdx.y;
  int gwin = win_base + lwin;
  int tid = threadIdx.x;
  const unsigned short* base = qkv + (size_t)lwin*NWIN*576 + head*HDn;
  for (int t = tid; t < NWIN*HDn; t += 256){
    int n = t >> 5, d = t & 31;
    const unsigned short* rp = base + (size_t)n*576 + d;
    qs[n][d] = bf2f(rp[0]) * QKSCALE;
    ks[n][d] = bf2f(rp[192]);
    vs[n][d] = bf2f(rp[384]);
  }
  __syncthreads();
  int rem = gwin & 63, wh = rem >> 3, ww = rem & 7;
  for (int t = tid; t < NWIN*NWIN; t += 256){
    int p = t / NWIN, q = t - p*NWIN;
    float acc = 0.f;
    #pragma unroll
    for (int d = 0; d < HDn; ++d) acc += qs[p][d]*ks[q][d];
    int pi = p/7, pj = p%7, qi = q/7, qj = q%7;
    int rel = (pi-qi+6)*13 + (pj-qj+6);
    acc += bias_table[rel*HEADSn + head];
    int pr = wh*7+pi, pc = ww*7+pj, qr = wh*7+qi, qc = ww*7+qj;
    int cp = (pr<49?0:(pr<53?1:2))*3 + (pc<49?0:(pc<53?1:2));
    int cq = (qr<49?0:(qr<53?1:2))*3 + (qc<49?0:(qc<53?1:2));
    if (cp != cq) acc -= 100.0f;
    S[p][q] = acc;
  }
  __syncthreads();
  if (tid < NWIN){
    float m = -1e30f;
    for (int q=0;q<NWIN;++q) m = fmaxf(m, S[tid][q]);
    float sum = 0.f;
    for (int q=0;q<NWIN;++q){ float e = expf(S[tid][q]-m); S[tid][q]=e; sum+=e; }
    float inv = 1.0f/sum;
    for (int q=0;q<NWIN;++q) S[tid][q] *= inv;
  }
  __syncthreads();
  for (int t = tid; t < NWIN*HDn; t += 256){
    int n = t >> 5, d = t & 31;
    float acc = 0.f;
    for (int m=0;m<NWIN;++m) acc += S[n][m]*vs[m][d];
    o[((size_t)gwin*NWIN + n)*Cn + head*HDn + d] = f2bf(acc);
  }
}

// ---------------- MFMA GEMM (m97 structure): C = A(bf16) * Bt(bf16)^T ----------------
// (kept for QKV / proj / FFN2; FFN1 conv uses the pipelined kernel below)
template<int AMODE, int EPI, int BMt, int BNt>
__global__ __launch_bounds__(256) void k_gemm(const unsigned short* __restrict__ A,
                                              const unsigned short* __restrict__ Bt,
                                              int K, int a_rbase, int o_rbase,
                                              const float* __restrict__ e0,
                                              const float* __restrict__ e1,
                                              const float* __restrict__ e2,
                                              void* __restrict__ out)
{
  constexpr int WMT = BMt/32, WNT = BNt/32;   // frags per wave
  constexpr int NIA = BMt/64, NIB = BNt/64;   // 64-row staging issues
  __shared__ __align__(16) unsigned short As[BMt*32];
  __shared__ __align__(16) unsigned short Bs[BNt*32];
  int tid = threadIdx.x;
  int bm = blockIdx.y * BMt, bn = blockIdx.x * BNt;
  int wave = tid >> 6, lane = tid & 63;
  int l15 = lane & 15, quad = lane >> 4;
  int wm = (wave & 1) * (BMt/2), wn = (wave >> 1) * (BNt/2);

  int srow = tid >> 2;          // staging row within a 64-row issue
  int kc   = (tid & 3) * 8;     // k element offset (8 bf16 = 16 B)

  size_t abase[NIA];
  #pragma unroll
  for (int i=0;i<NIA;++i){
    int lrow = bm + i*64 + srow;
    if (AMODE == 0) abase[i] = (size_t)(a_rbase + lrow) * K + kc;
    else {
      int grow = a_rbase + lrow;
      int b = grow / (Hn*Wn), rc = grow % (Hn*Wn);
      int r = rc / Wn, c = rc - r*Wn;
      abase[i] = (size_t)((b*PADH + r)*PADH + c) * Cn + kc;
    }
  }
  size_t bbase[NIB];
  #pragma unroll
  for (int i=0;i<NIB;++i) bbase[i] = (size_t)(bn + i*64 + srow) * K + kc;

  f32x4 acc[WMT][WNT] = {};

  int nkb = K / 32;
  for (int kb = 0; kb < nkb; ++kb){
    int k0 = kb * 32;
    size_t aoff;
    if (AMODE == 0) aoff = (size_t)k0;
    else {
      int tap = k0 / Cn, ci = k0 - tap*Cn;   // uniform across BK block
      int dh = tap/3, dw = tap - dh*3;
      aoff = (size_t)((dh*PADH + dw)*Cn + ci);
    }
    #pragma unroll
    for (int i=0;i<NIA;++i)
      gl16(A + abase[i] + aoff, &As[i*64*32] + (size_t)tid*8);
    #pragma unroll
    for (int i=0;i<NIB;++i)
      gl16(Bt + bbase[i] + (size_t)k0, &Bs[i*64*32] + (size_t)tid*8);
    __syncthreads();   // drains vmcnt: DMA complete

    bf16x8 af[WMT], bfr[WNT];
    #pragma unroll
    for (int mt=0;mt<WMT;++mt) af[mt]  = *(const bf16x8*)&As[(wm + mt*16 + l15)*32 + quad*8];
    #pragma unroll
    for (int nt=0;nt<WNT;++nt) bfr[nt] = *(const bf16x8*)&Bs[(wn + nt*16 + l15)*32 + quad*8];
    #pragma unroll
    for (int mt=0;mt<WMT;++mt)
      #pragma unroll
      for (int nt=0;nt<WNT;++nt)
        acc[mt][nt] = __builtin_amdgcn_mfma_f32_16x16x32_bf16(af[mt], bfr[nt], acc[mt][nt], 0,0,0);
    __syncthreads();   // all consumers done before next overwrite
  }

  #pragma unroll
  for (int mt=0; mt<WMT; ++mt)
  #pragma unroll
  for (int nt=0; nt<WNT; ++nt){
    f32x4 a4 = acc[mt][nt];
    int gcol = bn + wn + nt*16 + l15;
    #pragma unroll
    for (int r=0; r<4; ++r){
      int orow = bm + wm + mt*16 + quad*4 + r;   // chunk-local
      float v = a4[r];
      if (EPI == 0){
        v += e0[gcol];
        ((unsigned short*)out)[(size_t)orow*576 + gcol] = f2bf(v);
      } else if (EPI == 1){
        v += e0[gcol];
        int grow = o_rbase + orow;
        int win = grow / NWIN, n = grow - win*NWIN;
        int b = win >> 6, rem2 = win & 63, wh = rem2 >> 3, ww = rem2 & 7;
        int ii = n / WSz, jj = n - ii*WSz;
        int fr = (wh*WSz + ii + SHIFTn) % Hn;
        int fc = (ww*WSz + jj + SHIFTn) % Wn;
        size_t idx = (size_t)((b*Hn + fr)*Wn + fc)*Cn + gcol;
        ((float*)out)[idx] = e2[idx] + v;
      } else if (EPI == 2){
        v = v * e0[gcol] + e1[gcol];
        v = 0.5f * v * (1.0f + erff(v * 0.7071067811865476f));
        ((unsigned short*)out)[(size_t)orow*HIDDENn + gcol] = f2bf(v);
      } else {
        v = v * e0[gcol] + e1[gcol];
        int grow = o_rbase + orow;
        v += e2[(size_t)grow*Cn + gcol];
        ((float*)out)[(size_t)grow*Cn + gcol] = v;
      }
    }
  }
}

// ---------------- 4-phase 256x256x64 conv GEMM (FFN1: im2col + bn1 + exact GELU) ----------------
// Round-2 schedule (best measured): t+2 prefetch into the SAME buffer, vmcnt(8)
// counted wait once per tile, per-phase lgkmcnt(0)+sched_barrier(0) before MFMA
// (rule #18), inline-asm ds_read_b128 fragment loads, 16B-chunk XOR swizzle via
// inverse-permuted global source + swizzled read (rule #21).
// Round-3's proven addition kept: m204 bijective XCD swizzle (FETCH 194->74MB).
// Round-3's t+1 dbuf schedule REVERTED: it cut issue-to-retire distance below
// HBM latency (~900cyc) and regressed 378->450us.
__global__ __launch_bounds__(512, 1) void k_gemm8conv(
    const unsigned short* __restrict__ A,   // ln2pad, zero-padded [32][58][58][192] bf16
    const unsigned short* __restrict__ Bt,  // wTf1 [768][1728] bf16
    int a_rbase,
    const float* __restrict__ e0,           // bn1_scale
    const float* __restrict__ e1,           // bn1_shift
    unsigned short* __restrict__ out)       // hc [mc][768] bf16
{
  __shared__ __align__(16) unsigned short As[2*256*64];
  __shared__ __align__(16) unsigned short Bs[2*256*64];
  const int tid  = threadIdx.x;
  const int wave = tid >> 6, lane = tid & 63;
  const int l15  = lane & 15, quad = lane >> 4;
  const int wm   = (wave & 1) * 128;
  const int wn   = (wave >> 1) * 64;

  // T1: bijective XCD swizzle (m204) over the hardware linear dispatch id.
  const int nwg = gridDim.x * gridDim.y;
  const int lin = blockIdx.y * gridDim.x + blockIdx.x;
  const int q8 = nwg >> 3, r8 = nwg & 7;
  const int xcd = lin & 7, cidx = lin >> 3;
  const int swz = (xcd < r8 ? xcd*(q8+1) : r8*(q8+1) + (xcd - r8)*q8) + cidx;
  const int bn = (swz % gridDim.x) * 256;
  const int bm = (swz / gridDim.x) * 256;

  // staging geometry: one gl16 issue = 512 thr x 16B = 64 rows x 128B
  const int srow = tid >> 3;                  // row within issue
  const int scs  = (tid & 7) ^ (srow & 7);    // inverse-swizzled source chunk
  const int ldst = tid * 8;                   // linear LDS dest (shorts)

  size_t abase[4], bbase[4];
  #pragma unroll
  for (int i=0;i<4;++i){
    int grow = a_rbase + bm + i*64 + srow;
    int b = grow / (Hn*Wn), rc = grow % (Hn*Wn);
    int r = rc / Wn, c = rc - r*Wn;
    abase[i] = (size_t)((b*PADH + r)*PADH + c)*Cn + scs*8;
    bbase[i] = (size_t)(bn + i*64 + srow)*KCONV + scs*8;
  }

  // swizzled read chunk offsets (row&7 == l15&7 since all row bases are mult of 8)
  const int cx0 = ((quad    ) ^ (l15 & 7)) * 8;
  const int cx1 = ((quad + 4) ^ (l15 & 7)) * 8;

  f32x4 acc[8][4] = {};
  bf16x8 af[4][2], bfr[4][2];

  const int ntot = KCONV/64;   // 27 K-tiles

  // ---- prologue: stage tile0 -> buf0, tile1 -> buf1 (tile1: tap0, ci=64) ----
  #pragma unroll
  for (int i=0;i<4;++i) gl16(Bt + bbase[i],      Bs + i*4096 + ldst);
  #pragma unroll
  for (int i=0;i<4;++i) gl16(A  + abase[i],      As + i*4096 + ldst);
  #pragma unroll
  for (int i=0;i<4;++i) gl16(Bt + bbase[i] + 64, Bs + 16384 + i*4096 + ldst);
  #pragma unroll
  for (int i=0;i<4;++i) gl16(A  + abase[i] + 64, As + 16384 + i*4096 + ldst);
  asm volatile("s_waitcnt vmcnt(8)" ::: "memory");   // tile0 landed, tile1 in flight
  __builtin_amdgcn_s_barrier();

  for (int t = 0; t < ntot; ++t){
    const unsigned short* Ac = As + (t&1)*16384;
    const unsigned short* Bc = Bs + (t&1)*16384;
    unsigned short* Asn = As + (t&1)*16384;    // tile t+2 -> same buffer as t
    unsigned short* Bsn = Bs + (t&1)*16384;
    const bool pf = (t+2 < ntot);
    const int t2 = t + 2;
    const int tap2 = t2/3;
    const int dh2 = tap2/3, dw2 = tap2 - dh2*3, ci2 = (t2 - tap2*3)*64;
    const size_t aoff2 = (size_t)(dh2*PADH + dw2)*Cn + ci2;
    const size_t boff2 = (size_t)t2*64;

    // ---------- P1 ----------
    #pragma unroll
    for (int mt=0; mt<4; ++mt){
      const unsigned short* rp = Ac + (wm + mt*16 + l15)*64;
      af[mt][0] = dsr16(rp + cx0);
      af[mt][1] = dsr16(rp + cx1);
    }
    #pragma unroll
    for (int nn=0; nn<4; ++nn){
      const unsigned short* rp = Bc + (wn + nn*16 + l15)*64;
      bfr[nn][0] = dsr16(rp + cx0);
      bfr[nn][1] = dsr16(rp + cx1);
    }
    asm volatile("s_waitcnt lgkmcnt(0)" ::: "memory");
    __builtin_amdgcn_sched_barrier(0);
    __builtin_amdgcn_s_barrier();            // all B reads + A-half0 reads done block-wide
    if (pf){ gl16(Bt + bbase[0] + boff2, Bsn + 0*4096 + ldst);
             gl16(Bt + bbase[1] + boff2, Bsn + 1*4096 + ldst); }
    __builtin_amdgcn_s_setprio(1);
    #pragma unroll
    for (int mt=0; mt<4; ++mt)
      #pragma unroll
      for (int nn=0; nn<2; ++nn)
        #pragma unroll
        for (int kk=0; kk<2; ++kk)
          acc[mt][nn] = __builtin_amdgcn_mfma_f32_16x16x32_bf16(af[mt][kk], bfr[nn][kk], acc[mt][nn], 0,0,0);
    __builtin_amdgcn_s_setprio(0);
    __builtin_amdgcn_s_barrier();

    // ---------- P2 ----------
    if (pf){ gl16(Bt + bbase[2] + boff2, Bsn + 2*4096 + ldst);
             gl16(Bt + bbase[3] + boff2, Bsn + 3*4096 + ldst); }
    __builtin_amdgcn_s_setprio(1);
    #pragma unroll
    for (int mt=0; mt<4; ++mt)
      #pragma unroll
      for (int nn=2; nn<4; ++nn)
        #pragma unroll
        for (int kk=0; kk<2; ++kk)
          acc[mt][nn] = __builtin_amdgcn_mfma_f32_16x16x32_bf16(af[mt][kk], bfr[nn][kk], acc[mt][nn], 0,0,0);
    __builtin_amdgcn_s_setprio(0);
    __builtin_amdgcn_s_barrier();

    // ---------- P3 ----------
    #pragma unroll
    for (int mt=0; mt<4; ++mt){
      const unsigned short* rp = Ac + (wm + 64 + mt*16 + l15)*64;
      af[mt][0] = dsr16(rp + cx0);
      af[mt][1] = dsr16(rp + cx1);
    }
    asm volatile("s_waitcnt lgkmcnt(0)" ::: "memory");
    __builtin_amdgcn_sched_barrier(0);
    __builtin_amdgcn_s_barrier();            // all A reads of this buffer done block-wide
    if (pf){ gl16(A + abase[0] + aoff2, Asn + 0*4096 + ldst);
             gl16(A + abase[1] + aoff2, Asn + 1*4096 + ldst); }
    __builtin_amdgcn_s_setprio(1);
    #pragma unroll
    for (int mt=0; mt<4; ++mt)
      #pragma unroll
      for (int nn=0; nn<2; ++nn)
        #pragma unroll
        for (int kk=0; kk<2; ++kk)
          acc[4+mt][nn] = __builtin_amdgcn_mfma_f32_16x16x32_bf16(af[mt][kk], bfr[nn][kk], acc[4+mt][nn], 0,0,0);
    __builtin_amdgcn_s_setprio(0);
    __builtin_amdgcn_s_barrier();

    // ---------- P4 ----------
    if (pf){ gl16(A + abase[2] + aoff2, Asn + 2*4096 + ldst);
             gl16(A + abase[3] + aoff2, Asn + 3*4096 + ldst); }
    __builtin_amdgcn_s_setprio(1);
    #pragma unroll
    for (int mt=0; mt<4; ++mt)
      #pragma unroll
      for (int nn=2; nn<4; ++nn)
        #pragma unroll
        for (int kk=0; kk<2; ++kk)
          acc[4+mt][nn] = __builtin_amdgcn_mfma_f32_16x16x32_bf16(af[mt][kk], bfr[nn][kk], acc[4+mt][nn], 0,0,0);
    __builtin_amdgcn_s_setprio(0);
    if (pf)                  { asm volatile("s_waitcnt vmcnt(8)" ::: "memory"); }
    else if (t+1 < ntot)     { asm volatile("s_waitcnt vmcnt(0)" ::: "memory"); }
    __builtin_amdgcn_s_barrier();            // next tile's buffer fully staged block-wide
  }

  // ---- epilogue: bn1 scale/shift + exact GELU -> bf16 ----
  const int orow0 = bm + wm + quad*4;
  #pragma unroll
  for (int nn=0; nn<4; ++nn){
    int gcol = bn + wn + nn*16 + l15;
    float s0 = e0[gcol], s1 = e1[gcol];
    #pragma unroll
    for (int mt=0; mt<8; ++mt){
      #pragma unroll
      for (int r=0; r<4; ++r){
        float v = acc[mt][nn][r] * s0 + s1;
        v = 0.5f * v * (1.0f + erff(v * 0.7071067811865476f));
        out[(size_t)(orow0 + mt*16 + r)*HIDDENn + gcol] = f2bf(v);
      }
    }
  }
}

extern "C" void kernel_launch(void* const* d_in, const int* in_sizes, int n_in,
                              void* d_out, int out_size, void* d_ws, size_t ws_size,
                              hipStream_t stream)
{
  const float* x        = (const float*)d_in[0];
  const float* ln1_g    = (const float*)d_in[1];
  const float* ln1_b    = (const float*)d_in[2];
  const float* w_qkv    = (const float*)d_in[3];
  const float* b_qkv    = (const float*)d_in[4];
  const float* btab     = (const float*)d_in[5];
  const float* w_proj   = (const float*)d_in[6];
  const float* b_proj   = (const float*)d_in[7];
  const float* ln2_g    = (const float*)d_in[8];
  const float* ln2_b    = (const float*)d_in[9];
  const float* w_ffn1   = (const float*)d_in[10];
  const float* bn1_s    = (const float*)d_in[11];
  const float* bn1_sh   = (const float*)d_in[12];
  const float* w_ffn2   = (const float*)d_in[13];
  const float* bn2_s    = (const float*)d_in[14];
  const float* bn2_sh   = (const float*)d_in[15];

  // ---- workspace layout (xmid lives in d_out; obuf moved into ws region B) ----
  // region A (szA):  h [NPIX][192]bf16  ->  ln2pad [32][58][58][192]bf16
  // region B (bsz):  [qc (nq chunks) | obuf [NPIX][192]bf16]  ->  hc [mc_f][768]bf16
  // region D:        4 transposed bf16 weights
  // d_out:           xmid fp32 (proj output w/ residual) -> final out (in-place EPI3)
  const size_t szA   = 41337344;
  const int    nq    = 8;                                  // qkv/attn chunks (fixed)
  const size_t qc_sz = (size_t)NPIX*576*2/nq;              // 14,450,688
  const size_t ob_sz = (size_t)NPIX*Cn*2;                  // 38,535,168
  const size_t wtsz  = 221184 + 73728 + 2654208 + 294912;
  int nf = 8;                                              // ffn chunks: fewest that fit
  for (int cand = 1; cand <= 8; cand <<= 1){
    size_t bsz_c = (size_t)NPIX*HIDDENn*2/cand;
    if (bsz_c < qc_sz + ob_sz) bsz_c = qc_sz + ob_sz;
    if (szA + bsz_c + wtsz + (1u<<20) <= ws_size){ nf = cand; break; }
  }
  size_t bsz = (size_t)NPIX*HIDDENn*2/nf;
  if (bsz < qc_sz + ob_sz) bsz = qc_sz + ob_sz;
  const int mc_q = NPIX / nq;          // qkv rows per chunk
  const int wc_q = 2048 / nq;          // windows per chunk
  const int mc_f = NPIX / nf;          // ffn rows per chunk (mult of 256)

  char* ws = (char*)d_ws;
  unsigned short* h      = (unsigned short*)ws;                 // region A
  unsigned short* ln2pad = (unsigned short*)ws;
  unsigned short* qc     = (unsigned short*)(ws + szA);         // region B
  unsigned short* obuf   = (unsigned short*)(ws + szA + qc_sz);
  unsigned short* hc     = (unsigned short*)(ws + szA);
  size_t off = szA + bsz;
  unsigned short* wTq    = (unsigned short*)(ws + off);  off += 221184;
  unsigned short* wTp    = (unsigned short*)(ws + off);  off += 73728;
  unsigned short* wTf1   = (unsigned short*)(ws + off);  off += 2654208;
  unsigned short* wTf2   = (unsigned short*)(ws + off);
  float*          xmid   = (float*)d_out;    // residual stream, fp32
  float*          outp   = (float*)d_out;    // final output (in-place with xmid)

  dim3 blk(256);

  // weight transposes + bf16 cast (tiny)
  k_transpose<<<(192*576 + 255)/256,  blk, 0, stream>>>(w_qkv,  wTq,  192, 576);
  k_transpose<<<(192*192 + 255)/256,  blk, 0, stream>>>(w_proj, wTp,  192, 192);
  k_transpose<<<(1728*768 + 255)/256, blk, 0, stream>>>(w_ffn1, wTf1, 1728, 768);
  k_transpose<<<(768*192 + 255)/256,  blk, 0, stream>>>(w_ffn2, wTf2, 768, 192);

  // LN1 + roll + window partition (fp32 -> bf16)
  k_ln1<<<NPIX/4, blk, 0, stream>>>(x, ln1_g, ln1_b, h);

  // QKV GEMM + attention, nq chunks (obuf in ws region B, after qc)
  for (int c = 0; c < nq; ++c){
    int rbase = c * mc_q;
    k_gemm<0,0,128,64><<<dim3(576/64, mc_q/128), blk, 0, stream>>>(
        h, wTq, 192, rbase, 0, b_qkv, nullptr, nullptr, qc);
    k_attn<<<dim3(HEADSn, wc_q), blk, 0, stream>>>(qc, btab, obuf, c*wc_q);
  }

  // proj GEMM + window reverse + roll + shortcut(x fp32) -> xmid (= d_out fp32), full M
  k_gemm<0,1,128,64><<<dim3(192/64, NPIX/128), blk, 0, stream>>>(
      obuf, wTp, 192, 0, 0, b_proj, nullptr, x, xmid);

  // LN2 into zero-padded bf16 buffer (overwrites h; h is dead after qkv)
  hipMemsetAsync(ln2pad, 0, (size_t)Bn*PADH*PADH*Cn*2, stream);
  k_ln2<<<NPIX/4, blk, 0, stream>>>(xmid, ln2_g, ln2_b, ln2pad);

  // FFN: conv3x3(im2col, 256^2 pipelined)+bn1+GELU -> hc; conv1x1+bn2+residual -> d_out (in place)
  for (int c = 0; c < nf; ++c){
    int rbase = c * mc_f;
    k_gemm8conv<<<dim3(HIDDENn/256, mc_f/256), dim3(512), 0, stream>>>(
        ln2pad, wTf1, rbase, bn1_s, bn1_sh, hc);
    k_gemm<0,3,128,64><<<dim3(192/64, mc_f/128), blk, 0, stream>>>(
        hc, wTf2, 768, 0, rbase, bn2_s, bn2_sh, xmid, outp);
  }
}

// Round 5
// 1048.789 us; speedup vs baseline: 1.0916x; 1.0916x over previous
//
#include <hip/hip_runtime.h>
#include <hip/hip_bf16.h>
#include <math.h>

#define DEVINL __device__ __forceinline__

typedef __bf16 bf16x8 __attribute__((ext_vector_type(8)));
typedef float  f32x4  __attribute__((ext_vector_type(4)));
typedef unsigned int u32x4 __attribute__((ext_vector_type(4)));

DEVINL float bf2f(unsigned short h){ return __builtin_bit_cast(float, (unsigned)h << 16); }
DEVINL unsigned short f2bf(float f){
  unsigned u = __builtin_bit_cast(unsigned, f);
  u += 0x7fffu + ((u >> 16) & 1u);
  return (unsigned short)(u >> 16);
}

// direct global->LDS DMA, 16B per lane (lds dest must be wave-uniform base + lane*16)
DEVINL void gl16(const unsigned short* g, unsigned short* l){
  __builtin_amdgcn_global_load_lds((const __attribute__((address_space(1))) unsigned int*)g,
                                   (__attribute__((address_space(3))) unsigned int*)l,
                                   16, 0, 0);
}

// 32-bit LDS byte offset for inline-asm DS ops
DEVINL unsigned ldsoff(const void* p){
  return (unsigned)(unsigned long long)(const __attribute__((address_space(3))) char*)p;
}
// inline-asm ds_read_b128: opaque to the backend waitcnt/alias tracker.
// Caller must place counted s_waitcnt lgkmcnt + sched_barrier before consumers (rule #18).
DEVINL bf16x8 dsr16(const unsigned short* p){
  u32x4 r;
  asm volatile("ds_read_b128 %0, %1" : "=v"(r) : "v"(ldsoff(p)));
  return __builtin_bit_cast(bf16x8, r);
}

// ---- problem constants ----
#define Bn 32
#define Hn 56
#define Wn 56
#define Cn 192
#define WSz 7
#define SHIFTn 3
#define HEADSn 6
#define HDn 32
#define NWIN 49
#define NPIX (Bn*Hn*Wn)       /* 100352 == 2048*49 */
#define HIDDENn 768
#define KCONV (9*Cn)          /* 1728 */
#define PADH 58
#define QKSCALE 0.17677669529663687f

DEVINL float wave_sum(float v){
  #pragma unroll
  for (int off=32; off; off>>=1) v += __shfl_xor(v, off, 64);
  return v;
}

// ---------------- LN1 (fp32 in) + roll(-3,-3) + window partition -> h [100352][192] bf16 ----------------
__global__ __launch_bounds__(256) void k_ln1(const float* __restrict__ x,
                                             const float* __restrict__ g,
                                             const float* __restrict__ bb,
                                             unsigned short* __restrict__ h)
{
  int row  = blockIdx.x*4 + (threadIdx.x >> 6);
  int lane = threadIdx.x & 63;
  int win = row / NWIN, n = row % NWIN;
  int b = win >> 6, rem = win & 63, wh = rem >> 3, ww = rem & 7;
  int i = n / WSz, j = n % WSz;
  int rr = (wh*WSz + i + SHIFTn) % Hn;
  int cc = (ww*WSz + j + SHIFTn) % Wn;
  const float* xr = x + (size_t)((b*Hn + rr)*Wn + cc)*Cn;
  float v0 = xr[lane], v1 = xr[lane+64], v2 = xr[lane+128];
  float s  = wave_sum(v0+v1+v2);
  float sq = wave_sum(v0*v0+v1*v1+v2*v2);
  float mu = s * (1.0f/Cn);
  float var = sq * (1.0f/Cn) - mu*mu;
  float rs = rsqrtf(var + 1e-3f);
  unsigned short* hr = h + (size_t)row*Cn;
  hr[lane]     = f2bf((v0-mu)*rs*g[lane]     + bb[lane]);
  hr[lane+64]  = f2bf((v1-mu)*rs*g[lane+64]  + bb[lane+64]);
  hr[lane+128] = f2bf((v2-mu)*rs*g[lane+128] + bb[lane+128]);
}

// ---------------- LN2 on xmid(fp32) -> zero-padded bf16 buffer [32][58][58][192] ----------------
__global__ __launch_bounds__(256) void k_ln2(const float* __restrict__ xmid,
                                             const float* __restrict__ g,
                                             const float* __restrict__ bb,
                                             unsigned short* __restrict__ out)
{
  int p    = blockIdx.x*4 + (threadIdx.x >> 6);
  int lane = threadIdx.x & 63;
  int b = p / (Hn*Wn), rc = p % (Hn*Wn);
  int r = rc / Wn, c = rc % Wn;
  const float* xr = xmid + (size_t)p*Cn;
  float v0 = xr[lane], v1 = xr[lane+64], v2 = xr[lane+128];
  float s  = wave_sum(v0+v1+v2);
  float sq = wave_sum(v0*v0+v1*v1+v2*v2);
  float mu = s * (1.0f/Cn);
  float var = sq * (1.0f/Cn) - mu*mu;
  float rs = rsqrtf(var + 1e-3f);
  unsigned short* orow = out + (size_t)((b*PADH + r + 1)*PADH + (c + 1))*Cn;
  orow[lane]     = f2bf((v0-mu)*rs*g[lane]     + bb[lane]);
  orow[lane+64]  = f2bf((v1-mu)*rs*g[lane+64]  + bb[lane+64]);
  orow[lane+128] = f2bf((v2-mu)*rs*g[lane+128] + bb[lane+128]);
}

// ---------------- transpose + fp32->bf16: out[n*K+k] = bf16(in[k*N+n]) ----------------
__global__ __launch_bounds__(256) void k_transpose(const float* __restrict__ in,
                                                   unsigned short* __restrict__ out,
                                                   int K, int N)
{
  int idx = blockIdx.x*256 + threadIdx.x;
  if (idx < K*N){ int k = idx / N, n = idx - k*N; out[(size_t)n*K + k] = f2bf(in[idx]); }
}

// ---------------- fused windowed attention: one block per (head, chunk-local window) ----------------
__global__ __launch_bounds__(256) void k_attn(const unsigned short* __restrict__ qkv, // chunk-local bf16
                                              const float* __restrict__ bias_table,   // fp32
                                              unsigned short* __restrict__ o,          // global rows bf16
                                              int win_base)
{
  __shared__ float qs[NWIN][HDn], ks[NWIN][HDn], vs[NWIN][HDn], S[NWIN][NWIN+1];
  int head = blockIdx.x, lwin = blockIdx.y;
  int gwin = win_base + lwin;
  int tid = threadIdx.x;
  const unsigned short* base = qkv + (size_t)lwin*NWIN*576 + head*HDn;
  for (int t = tid; t < NWIN*HDn; t += 256){
    int n = t >> 5, d = t & 31;
    const unsigned short* rp = base + (size_t)n*576 + d;
    qs[n][d] = bf2f(rp[0]) * QKSCALE;
    ks[n][d] = bf2f(rp[192]);
    vs[n][d] = bf2f(rp[384]);
  }
  __syncthreads();
  int rem = gwin & 63, wh = rem >> 3, ww = rem & 7;
  for (int t = tid; t < NWIN*NWIN; t += 256){
    int p = t / NWIN, q = t - p*NWIN;
    float acc = 0.f;
    #pragma unroll
    for (int d = 0; d < HDn; ++d) acc += qs[p][d]*ks[q][d];
    int pi = p/7, pj = p%7, qi = q/7, qj = q%7;
    int rel = (pi-qi+6)*13 + (pj-qj+6);
    acc += bias_table[rel*HEADSn + head];
    int pr = wh*7+pi, pc = ww*7+pj, qr = wh*7+qi, qc = ww*7+qj;
    int cp = (pr<49?0:(pr<53?1:2))*3 + (pc<49?0:(pc<53?1:2));
    int cq = (qr<49?0:(qr<53?1:2))*3 + (qc<49?0:(qc<53?1:2));
    if (cp != cq) acc -= 100.0f;
    S[p][q] = acc;
  }
  __syncthreads();
  if (tid < NWIN){
    float m = -1e30f;
    for (int q=0;q<NWIN;++q) m = fmaxf(m, S[tid][q]);
    float sum = 0.f;
    for (int q=0;q<NWIN;++q){ float e = expf(S[tid][q]-m); S[tid][q]=e; sum+=e; }
    float inv = 1.0f/sum;
    for (int q=0;q<NWIN;++q) S[tid][q] *= inv;
  }
  __syncthreads();
  for (int t = tid; t < NWIN*HDn; t += 256){
    int n = t >> 5, d = t & 31;
    float acc = 0.f;
    for (int m=0;m<NWIN;++m) acc += S[n][m]*vs[m][d];
    o[((size_t)gwin*NWIN + n)*Cn + head*HDn + d] = f2bf(acc);
  }
}

// ---------------- MFMA GEMM (m97 structure): C = A(bf16) * Bt(bf16)^T ----------------
// (kept for QKV / proj / FFN2; FFN1 conv uses the pipelined kernel below)
template<int AMODE, int EPI, int BMt, int BNt>
__global__ __launch_bounds__(256) void k_gemm(const unsigned short* __restrict__ A,
                                              const unsigned short* __restrict__ Bt,
                                              int K, int a_rbase, int o_rbase,
                                              const float* __restrict__ e0,
                                              const float* __restrict__ e1,
                                              const float* __restrict__ e2,
                                              void* __restrict__ out)
{
  constexpr int WMT = BMt/32, WNT = BNt/32;   // frags per wave
  constexpr int NIA = BMt/64, NIB = BNt/64;   // 64-row staging issues
  __shared__ __align__(16) unsigned short As[BMt*32];
  __shared__ __align__(16) unsigned short Bs[BNt*32];
  int tid = threadIdx.x;
  int bm = blockIdx.y * BMt, bn = blockIdx.x * BNt;
  int wave = tid >> 6, lane = tid & 63;
  int l15 = lane & 15, quad = lane >> 4;
  int wm = (wave & 1) * (BMt/2), wn = (wave >> 1) * (BNt/2);

  int srow = tid >> 2;          // staging row within a 64-row issue
  int kc   = (tid & 3) * 8;     // k element offset (8 bf16 = 16 B)

  size_t abase[NIA];
  #pragma unroll
  for (int i=0;i<NIA;++i){
    int lrow = bm + i*64 + srow;
    if (AMODE == 0) abase[i] = (size_t)(a_rbase + lrow) * K + kc;
    else {
      int grow = a_rbase + lrow;
      int b = grow / (Hn*Wn), rc = grow % (Hn*Wn);
      int r = rc / Wn, c = rc - r*Wn;
      abase[i] = (size_t)((b*PADH + r)*PADH + c) * Cn + kc;
    }
  }
  size_t bbase[NIB];
  #pragma unroll
  for (int i=0;i<NIB;++i) bbase[i] = (size_t)(bn + i*64 + srow) * K + kc;

  f32x4 acc[WMT][WNT] = {};

  int nkb = K / 32;
  for (int kb = 0; kb < nkb; ++kb){
    int k0 = kb * 32;
    size_t aoff;
    if (AMODE == 0) aoff = (size_t)k0;
    else {
      int tap = k0 / Cn, ci = k0 - tap*Cn;   // uniform across BK block
      int dh = tap/3, dw = tap - dh*3;
      aoff = (size_t)((dh*PADH + dw)*Cn + ci);
    }
    #pragma unroll
    for (int i=0;i<NIA;++i)
      gl16(A + abase[i] + aoff, &As[i*64*32] + (size_t)tid*8);
    #pragma unroll
    for (int i=0;i<NIB;++i)
      gl16(Bt + bbase[i] + (size_t)k0, &Bs[i*64*32] + (size_t)tid*8);
    __syncthreads();   // drains vmcnt: DMA complete

    bf16x8 af[WMT], bfr[WNT];
    #pragma unroll
    for (int mt=0;mt<WMT;++mt) af[mt]  = *(const bf16x8*)&As[(wm + mt*16 + l15)*32 + quad*8];
    #pragma unroll
    for (int nt=0;nt<WNT;++nt) bfr[nt] = *(const bf16x8*)&Bs[(wn + nt*16 + l15)*32 + quad*8];
    #pragma unroll
    for (int mt=0;mt<WMT;++mt)
      #pragma unroll
      for (int nt=0;nt<WNT;++nt)
        acc[mt][nt] = __builtin_amdgcn_mfma_f32_16x16x32_bf16(af[mt], bfr[nt], acc[mt][nt], 0,0,0);
    __syncthreads();   // all consumers done before next overwrite
  }

  #pragma unroll
  for (int mt=0; mt<WMT; ++mt)
  #pragma unroll
  for (int nt=0; nt<WNT; ++nt){
    f32x4 a4 = acc[mt][nt];
    int gcol = bn + wn + nt*16 + l15;
    #pragma unroll
    for (int r=0; r<4; ++r){
      int orow = bm + wm + mt*16 + quad*4 + r;   // chunk-local
      float v = a4[r];
      if (EPI == 0){
        v += e0[gcol];
        ((unsigned short*)out)[(size_t)orow*576 + gcol] = f2bf(v);
      } else if (EPI == 1){
        v += e0[gcol];
        int grow = o_rbase + orow;
        int win = grow / NWIN, n = grow - win*NWIN;
        int b = win >> 6, rem2 = win & 63, wh = rem2 >> 3, ww = rem2 & 7;
        int ii = n / WSz, jj = n - ii*WSz;
        int fr = (wh*WSz + ii + SHIFTn) % Hn;
        int fc = (ww*WSz + jj + SHIFTn) % Wn;
        size_t idx = (size_t)((b*Hn + fr)*Wn + fc)*Cn + gcol;
        ((float*)out)[idx] = e2[idx] + v;
      } else if (EPI == 2){
        v = v * e0[gcol] + e1[gcol];
        v = 0.5f * v * (1.0f + erff(v * 0.7071067811865476f));
        ((unsigned short*)out)[(size_t)orow*HIDDENn + gcol] = f2bf(v);
      } else {
        v = v * e0[gcol] + e1[gcol];
        int grow = o_rbase + orow;
        v += e2[(size_t)grow*Cn + gcol];
        ((float*)out)[(size_t)grow*Cn + gcol] = v;
      }
    }
  }
}

// ---------------- 256x256x64 conv GEMM (FFN1: im2col + bn1 + exact GELU) ----------------
// Dataflow = round-2 (proven): t+2 prefetch into the SAME buffer, stage order
// B0-3 then A0-3, vmcnt(8) counted retire once per tile.
// NEW: per-wave COUNTED lgkm waits instead of block-wide drains. Reads are issued
// A-half0(8) then B-all(8); lgkmcnt(4) releases Q(M0,N01) (12 oldest = A0+B0,B1),
// lgkmcnt(0) releases Q(M0,N23). Block barrier AFTER the MFMA cluster (authorizes
// same-buffer stage), not before it -> DS pipe drains under MFMA shadow, each wave
// advances on its own reads. 3 barriers/tile (was 7). Rule #18 sched_barrier(0)
// after every counted wait. XOR swizzle (rule #21) + m204 XCD swizzle retained.
__global__ __launch_bounds__(512, 1) void k_gemm8conv(
    const unsigned short* __restrict__ A,   // ln2pad, zero-padded [32][58][58][192] bf16
    const unsigned short* __restrict__ Bt,  // wTf1 [768][1728] bf16
    int a_rbase,
    const float* __restrict__ e0,           // bn1_scale
    const float* __restrict__ e1,           // bn1_shift
    unsigned short* __restrict__ out)       // hc [mc][768] bf16
{
  __shared__ __align__(16) unsigned short As[2*256*64];
  __shared__ __align__(16) unsigned short Bs[2*256*64];
  const int tid  = threadIdx.x;
  const int wave = tid >> 6, lane = tid & 63;
  const int l15  = lane & 15, quad = lane >> 4;
  const int wm   = (wave & 1) * 128;
  const int wn   = (wave >> 1) * 64;

  // T1: bijective XCD swizzle (m204) over the hardware linear dispatch id.
  const int nwg = gridDim.x * gridDim.y;
  const int lin = blockIdx.y * gridDim.x + blockIdx.x;
  const int q8 = nwg >> 3, r8 = nwg & 7;
  const int xcd = lin & 7, cidx = lin >> 3;
  const int swz = (xcd < r8 ? xcd*(q8+1) : r8*(q8+1) + (xcd - r8)*q8) + cidx;
  const int bn = (swz % gridDim.x) * 256;
  const int bm = (swz / gridDim.x) * 256;

  // staging geometry: one gl16 issue = 512 thr x 16B = 64 rows x 128B
  const int srow = tid >> 3;                  // row within issue
  const int scs  = (tid & 7) ^ (srow & 7);    // inverse-swizzled source chunk
  const int ldst = tid * 8;                   // linear LDS dest (shorts)

  size_t abase[4], bbase[4];
  #pragma unroll
  for (int i=0;i<4;++i){
    int grow = a_rbase + bm + i*64 + srow;
    int b = grow / (Hn*Wn), rc = grow % (Hn*Wn);
    int r = rc / Wn, c = rc - r*Wn;
    abase[i] = (size_t)((b*PADH + r)*PADH + c)*Cn + scs*8;
    bbase[i] = (size_t)(bn + i*64 + srow)*KCONV + scs*8;
  }

  // swizzled read chunk offsets (row&7 == l15&7 since all row bases are mult of 8)
  const int cx0 = ((quad    ) ^ (l15 & 7)) * 8;
  const int cx1 = ((quad + 4) ^ (l15 & 7)) * 8;

  f32x4 acc[8][4] = {};
  bf16x8 af[4][2], bfr[4][2];

  const int ntot = KCONV/64;   // 27 K-tiles

  // ---- prologue: stage tile0 -> buf0, tile1 -> buf1 (tile1: tap0, ci=64) ----
  #pragma unroll
  for (int i=0;i<4;++i) gl16(Bt + bbase[i],      Bs + i*4096 + ldst);
  #pragma unroll
  for (int i=0;i<4;++i) gl16(A  + abase[i],      As + i*4096 + ldst);
  #pragma unroll
  for (int i=0;i<4;++i) gl16(Bt + bbase[i] + 64, Bs + 16384 + i*4096 + ldst);
  #pragma unroll
  for (int i=0;i<4;++i) gl16(A  + abase[i] + 64, As + 16384 + i*4096 + ldst);
  asm volatile("s_waitcnt vmcnt(8)" ::: "memory");   // tile0 landed, tile1 in flight
  __builtin_amdgcn_s_barrier();

  for (int t = 0; t < ntot; ++t){
    const unsigned short* Ac = As + (t&1)*16384;
    const unsigned short* Bc = Bs + (t&1)*16384;
    unsigned short* Asn = As + (t&1)*16384;    // tile t+2 -> same buffer as t
    unsigned short* Bsn = Bs + (t&1)*16384;
    const bool pf = (t+2 < ntot);
    const int t2 = t + 2;
    const int tap2 = t2/3;
    const int dh2 = tap2/3, dw2 = tap2 - dh2*3, ci2 = (t2 - tap2*3)*64;
    const size_t aoff2 = (size_t)(dh2*PADH + dw2)*Cn + ci2;
    const size_t boff2 = (size_t)t2*64;

    // ---- issue reads in consumption order: A-half0 (8), then B (8) ----
    #pragma unroll
    for (int mt=0; mt<4; ++mt){
      const unsigned short* rp = Ac + (wm + mt*16 + l15)*64;
      af[mt][0] = dsr16(rp + cx0);
      af[mt][1] = dsr16(rp + cx1);
    }
    #pragma unroll
    for (int nn=0; nn<4; ++nn){
      const unsigned short* rp = Bc + (wn + nn*16 + l15)*64;
      bfr[nn][0] = dsr16(rp + cx0);
      bfr[nn][1] = dsr16(rp + cx1);
    }
    // Q(M0,N0-1): needs 12 oldest reads (A0 x8 + B0,B1 x4) -> counted wait
    asm volatile("s_waitcnt lgkmcnt(4)" ::: "memory");
    __builtin_amdgcn_sched_barrier(0);
    __builtin_amdgcn_s_setprio(1);
    #pragma unroll
    for (int mt=0; mt<4; ++mt)
      #pragma unroll
      for (int nn=0; nn<2; ++nn)
        #pragma unroll
        for (int kk=0; kk<2; ++kk)
          acc[mt][nn] = __builtin_amdgcn_mfma_f32_16x16x32_bf16(af[mt][kk], bfr[nn][kk], acc[mt][nn], 0,0,0);
    __builtin_amdgcn_s_setprio(0);
    // Q(M0,N2-3): remaining 4 B reads
    asm volatile("s_waitcnt lgkmcnt(0)" ::: "memory");
    __builtin_amdgcn_sched_barrier(0);
    __builtin_amdgcn_s_setprio(1);
    #pragma unroll
    for (int mt=0; mt<4; ++mt)
      #pragma unroll
      for (int nn=2; nn<4; ++nn)
        #pragma unroll
        for (int kk=0; kk<2; ++kk)
          acc[mt][nn] = __builtin_amdgcn_mfma_f32_16x16x32_bf16(af[mt][kk], bfr[nn][kk], acc[mt][nn], 0,0,0);
    __builtin_amdgcn_s_setprio(0);
    __builtin_amdgcn_s_barrier();            // all waves done reading A0 + B of buf cur
    if (pf){ gl16(Bt + bbase[0] + boff2, Bsn + 0*4096 + ldst);
             gl16(Bt + bbase[1] + boff2, Bsn + 1*4096 + ldst);
             gl16(Bt + bbase[2] + boff2, Bsn + 2*4096 + ldst);
             gl16(Bt + bbase[3] + boff2, Bsn + 3*4096 + ldst); }

    // ---- A-half1 ----
    #pragma unroll
    for (int mt=0; mt<4; ++mt){
      const unsigned short* rp = Ac + (wm + 64 + mt*16 + l15)*64;
      af[mt][0] = dsr16(rp + cx0);
      af[mt][1] = dsr16(rp + cx1);
    }
    asm volatile("s_waitcnt lgkmcnt(0)" ::: "memory");
    __builtin_amdgcn_sched_barrier(0);
    __builtin_amdgcn_s_setprio(1);
    #pragma unroll
    for (int mt=0; mt<4; ++mt)
      #pragma unroll
      for (int nn=0; nn<4; ++nn)
        #pragma unroll
        for (int kk=0; kk<2; ++kk)
          acc[4+mt][nn] = __builtin_amdgcn_mfma_f32_16x16x32_bf16(af[mt][kk], bfr[nn][kk], acc[4+mt][nn], 0,0,0);
    __builtin_amdgcn_s_setprio(0);
    __builtin_amdgcn_s_barrier();            // all waves done reading A-half1 of buf cur
    if (pf){ gl16(A + abase[0] + aoff2, Asn + 0*4096 + ldst);
             gl16(A + abase[1] + aoff2, Asn + 1*4096 + ldst);
             gl16(A + abase[2] + aoff2, Asn + 2*4096 + ldst);
             gl16(A + abase[3] + aoff2, Asn + 3*4096 + ldst); }
    if (pf)                  { asm volatile("s_waitcnt vmcnt(8)" ::: "memory"); }
    else if (t+1 < ntot)     { asm volatile("s_waitcnt vmcnt(0)" ::: "memory"); }
    __builtin_amdgcn_s_barrier();            // next tile's buffer fully staged block-wide
  }

  // ---- epilogue: bn1 scale/shift + exact GELU -> bf16 ----
  const int orow0 = bm + wm + quad*4;
  #pragma unroll
  for (int nn=0; nn<4; ++nn){
    int gcol = bn + wn + nn*16 + l15;
    float s0 = e0[gcol], s1 = e1[gcol];
    #pragma unroll
    for (int mt=0; mt<8; ++mt){
      #pragma unroll
      for (int r=0; r<4; ++r){
        float v = acc[mt][nn][r] * s0 + s1;
        v = 0.5f * v * (1.0f + erff(v * 0.7071067811865476f));
        out[(size_t)(orow0 + mt*16 + r)*HIDDENn + gcol] = f2bf(v);
      }
    }
  }
}

extern "C" void kernel_launch(void* const* d_in, const int* in_sizes, int n_in,
                              void* d_out, int out_size, void* d_ws, size_t ws_size,
                              hipStream_t stream)
{
  const float* x        = (const float*)d_in[0];
  const float* ln1_g    = (const float*)d_in[1];
  const float* ln1_b    = (const float*)d_in[2];
  const float* w_qkv    = (const float*)d_in[3];
  const float* b_qkv    = (const float*)d_in[4];
  const float* btab     = (const float*)d_in[5];
  const float* w_proj   = (const float*)d_in[6];
  const float* b_proj   = (const float*)d_in[7];
  const float* ln2_g    = (const float*)d_in[8];
  const float* ln2_b    = (const float*)d_in[9];
  const float* w_ffn1   = (const float*)d_in[10];
  const float* bn1_s    = (const float*)d_in[11];
  const float* bn1_sh   = (const float*)d_in[12];
  const float* w_ffn2   = (const float*)d_in[13];
  const float* bn2_s    = (const float*)d_in[14];
  const float* bn2_sh   = (const float*)d_in[15];

  // ---- workspace layout (xmid lives in d_out; adaptive unified chunking) ----
  // region A (szA):  h [NPIX][192]bf16  ->  ln2pad [32][58][58][192]bf16
  // region B (bsz):  [qc (nch chunks) | obuf [NPIX][192]bf16]  ->  hc [NPIX/nch][768]bf16
  // region D:        4 transposed bf16 weights
  // d_out:           xmid fp32 (proj output w/ residual) -> final out (in-place EPI3)
  const size_t szA   = 41337344;
  const size_t ob_sz = (size_t)NPIX*Cn*2;                  // 38,535,168
  const size_t wtsz  = 221184 + 73728 + 2654208 + 294912;
  int nch = 8;
  for (int cand = 1; cand <= 8; cand <<= 1){
    size_t qcsz  = (size_t)NPIX*1152/cand;                 // qkv chunk bf16
    size_t hcsz  = (size_t)NPIX*1536/cand;                 // hidden chunk bf16
    size_t bsz_c = qcsz + ob_sz;
    if (hcsz > bsz_c) bsz_c = hcsz;
    if (szA + bsz_c + wtsz + (1u<<20) <= ws_size){ nch = cand; break; }
  }
  const size_t qc_sz = (size_t)NPIX*1152/nch;
  size_t bsz = qc_sz + ob_sz;
  { size_t hcsz = (size_t)NPIX*1536/nch; if (hcsz > bsz) bsz = hcsz; }
  const int mc = NPIX / nch;           // rows per chunk (mult of 256: 100352 = 392*256)
  const int wc = 2048 / nch;           // windows per chunk

  char* ws = (char*)d_ws;
  unsigned short* h      = (unsigned short*)ws;                 // region A
  unsigned short* ln2pad = (unsigned short*)ws;
  unsigned short* qc     = (unsigned short*)(ws + szA);         // region B
  unsigned short* obuf   = (unsigned short*)(ws + szA + qc_sz);
  unsigned short* hc     = (unsigned short*)(ws + szA);
  size_t off = szA + bsz;
  unsigned short* wTq    = (unsigned short*)(ws + off);  off += 221184;
  unsigned short* wTp    = (unsigned short*)(ws + off);  off += 73728;
  unsigned short* wTf1   = (unsigned short*)(ws + off);  off += 2654208;
  unsigned short* wTf2   = (unsigned short*)(ws + off);
  float*          xmid   = (float*)d_out;    // residual stream, fp32
  float*          outp   = (float*)d_out;    // final output (in-place with xmid)

  dim3 blk(256);

  // weight transposes + bf16 cast (tiny)
  k_transpose<<<(192*576 + 255)/256,  blk, 0, stream>>>(w_qkv,  wTq,  192, 576);
  k_transpose<<<(192*192 + 255)/256,  blk, 0, stream>>>(w_proj, wTp,  192, 192);
  k_transpose<<<(1728*768 + 255)/256, blk, 0, stream>>>(w_ffn1, wTf1, 1728, 768);
  k_transpose<<<(768*192 + 255)/256,  blk, 0, stream>>>(w_ffn2, wTf2, 768, 192);

  // LN1 + roll + window partition (fp32 -> bf16)
  k_ln1<<<NPIX/4, blk, 0, stream>>>(x, ln1_g, ln1_b, h);

  // QKV GEMM + attention, nch chunks (obuf in ws region B, after qc)
  for (int c = 0; c < nch; ++c){
    int rbase = c * mc;
    k_gemm<0,0,128,64><<<dim3(576/64, mc/128), blk, 0, stream>>>(
        h, wTq, 192, rbase, 0, b_qkv, nullptr, nullptr, qc);
    k_attn<<<dim3(HEADSn, wc), blk, 0, stream>>>(qc, btab, obuf, c*wc);
  }

  // proj GEMM + window reverse + roll + shortcut(x fp32) -> xmid (= d_out fp32), full M
  k_gemm<0,1,128,64><<<dim3(192/64, NPIX/128), blk, 0, stream>>>(
      obuf, wTp, 192, 0, 0, b_proj, nullptr, x, xmid);

  // LN2 into zero-padded bf16 buffer (overwrites h; h is dead after qkv)
  hipMemsetAsync(ln2pad, 0, (size_t)Bn*PADH*PADH*Cn*2, stream);
  k_ln2<<<NPIX/4, blk, 0, stream>>>(xmid, ln2_g, ln2_b, ln2pad);

  // FFN: conv3x3(im2col, 256^2 pipelined)+bn1+GELU -> hc; conv1x1+bn2+residual -> d_out (in place)
  for (int c = 0; c < nch; ++c){
    int rbase = c * mc;
    k_gemm8conv<<<dim3(HIDDENn/256, mc/256), dim3(512), 0, stream>>>(
        ln2pad, wTf1, rbase, bn1_s, bn1_sh, hc);
    k_gemm<0,3,128,64><<<dim3(192/64, mc/128), blk, 0, stream>>>(
        hc, wTf2, 768, 0, rbase, bn2_s, bn2_sh, xmid, outp);
  }
}